// Round 1
// baseline (492.843 us; speedup 1.0000x reference)
//
#include <hip/hip_runtime.h>
#include <hip/hip_bf16.h>

#define HIDDEN 1024
#define INTER  2048
#define NEXP   8
#define BM 128
#define BN 128
#define BK 64

typedef __bf16 bf16_t;
typedef __bf16 bf16x4 __attribute__((ext_vector_type(4)));
typedef __bf16 bf16x8 __attribute__((ext_vector_type(8)));
typedef float  f32x4  __attribute__((ext_vector_type(4)));

__device__ __forceinline__ void async_cp16(const bf16_t* g, bf16_t* l) {
    __builtin_amdgcn_global_load_lds(
        (const __attribute__((address_space(1))) unsigned int*)g,
        (__attribute__((address_space(3))) unsigned int*)l, 16, 0, 0);
}

// hdr: [0..7]=cnt2 [8..15]=cnt1 [24..31]=seg_base [32..39]=seg_cap

// ---------------- Router: fp64 logits, NO global atomics ----------------------
__global__ __launch_bounds__(256) void router_kernel(
    const float* __restrict__ x, const float* __restrict__ wr,
    int* __restrict__ top_e, float* __restrict__ top_w,
    float* __restrict__ psums, bf16_t* __restrict__ xbf)
{
    __shared__ float wl[NEXP * HIDDEN];   // [e][h], 32 KB
    __shared__ float psl[4][NEXP];
    int tid = threadIdx.x;

    for (int i = tid; i < HIDDEN * NEXP / 4; i += 256) {
        float4 v = *(const float4*)(wr + i * 4);
        int m = i * 4, h = m >> 3, e = m & 7;
        wl[(e + 0) * HIDDEN + h] = v.x;
        wl[(e + 1) * HIDDEN + h] = v.y;
        wl[(e + 2) * HIDDEN + h] = v.z;
        wl[(e + 3) * HIDDEN + h] = v.w;
    }
    __syncthreads();

    int lane = tid & 63, wave = tid >> 6;
    int tok = blockIdx.x * 4 + wave;
    const float* xr = x + (size_t)tok * HIDDEN;

    float xv[16];
#pragma unroll
    for (int j = 0; j < 16; j++) xv[j] = xr[lane + 64 * j];

    bf16_t* xbr = xbf + (size_t)tok * HIDDEN;
#pragma unroll
    for (int j = 0; j < 16; j++) xbr[lane + 64 * j] = (bf16_t)xv[j];

    double acc[NEXP];
#pragma unroll
    for (int e = 0; e < NEXP; e++) acc[e] = 0.0;
#pragma unroll
    for (int j = 0; j < 16; j++) {
        int h = lane + 64 * j;
#pragma unroll
        for (int e = 0; e < NEXP; e++)
            acc[e] += (double)xv[j] * (double)wl[e * HIDDEN + h];
    }
#pragma unroll
    for (int e = 0; e < NEXP; e++) {
        double v = acc[e];
#pragma unroll
        for (int off = 32; off > 0; off >>= 1) v += __shfl_down(v, off);
        acc[e] = v;
    }
    if (lane == 0) {
        int e0 = 0;
#pragma unroll
        for (int e = 1; e < NEXP; e++) if (acc[e] > acc[e0]) e0 = e;
        int e1 = (e0 == 0) ? 1 : 0;
#pragma unroll
        for (int e = 0; e < NEXP; e++) if (e != e0 && acc[e] > acc[e1]) e1 = e;
        double w0 = 1.0 / (1.0 + exp(acc[e1] - acc[e0]));
        top_e[tok * 2 + 0] = e0;
        top_e[tok * 2 + 1] = e1;
        top_w[tok * 2 + 0] = (float)w0;
        top_w[tok * 2 + 1] = (float)(1.0 - w0);
        float mx = (float)acc[0];
#pragma unroll
        for (int e = 1; e < NEXP; e++) mx = fmaxf(mx, (float)acc[e]);
        float p[NEXP], s = 0.f;
#pragma unroll
        for (int e = 0; e < NEXP; e++) { p[e] = __expf((float)acc[e] - mx); s += p[e]; }
#pragma unroll
        for (int e = 0; e < NEXP; e++) psl[wave][e] = p[e] / s;
    }
    __syncthreads();
    if (tid < NEXP)
        psums[blockIdx.x * NEXP + tid] =
            psl[0][tid] + psl[1][tid] + psl[2][tid] + psl[3][tid];
}

// ------- Single-block: histogram + segments + aux + deterministic scatter -----
__global__ __launch_bounds__(256) void setup_scatter_kernel(
    const int* __restrict__ top_e, const float* __restrict__ psums, int nblk,
    int* __restrict__ hdr, int* __restrict__ row_tok, int* __restrict__ row_of,
    float* __restrict__ aux_out, int n)
{
    __shared__ int wcnt[4][16];
    __shared__ int sc1[NEXP], sc2[NEXP], segb[NEXP], segc[NEXP], cur[NEXP];
    __shared__ int woff[4][16];
    __shared__ float pred[NEXP];

    int tid = threadIdx.x, lane = tid & 63, wave = tid >> 6;
    if (tid < NEXP) pred[tid] = 0.f;

    int c1[NEXP] = {}, c2[NEXP] = {};
    for (int base = 0; base < n; base += 256) {
        int t = base + tid;
        int e0 = top_e[t * 2 + 0];
        int e1 = top_e[t * 2 + 1];
#pragma unroll
        for (int e = 0; e < NEXP; e++) {
            unsigned long long m0 = __ballot(e0 == e);
            unsigned long long m1 = __ballot(e1 == e);
            if (lane == 0) {
                c1[e] += __popcll(m0);
                c2[e] += __popcll(m0) + __popcll(m1);
            }
        }
    }
    if (lane == 0) {
#pragma unroll
        for (int e = 0; e < NEXP; e++) {
            wcnt[wave][e] = c2[e];
            wcnt[wave][8 + e] = c1[e];
        }
    }
    __syncthreads();
    if (tid < 16) {
        int s = wcnt[0][tid] + wcnt[1][tid] + wcnt[2][tid] + wcnt[3][tid];
        if (tid < 8) sc2[tid] = s; else sc1[tid - 8] = s;
    }
    __syncthreads();
    if (tid == 0) {
        int off = 0;
#pragma unroll
        for (int e = 0; e < NEXP; e++) {
            segb[e] = off; cur[e] = off;
            int cap = (sc2[e] + BM - 1) / BM * BM;
            segc[e] = cap; off += cap;
            hdr[e] = sc2[e]; hdr[8 + e] = sc1[e];
            hdr[24 + e] = segb[e]; hdr[32 + e] = cap;
        }
    }
    {
        float ps = 0.f;
        int e = tid & 7;
        for (int i = tid >> 3; i < nblk; i += 32) ps += psums[i * NEXP + e];
        ps += __shfl_down(ps, 32);
        ps += __shfl_down(ps, 16);
        ps += __shfl_down(ps, 8);
        if (lane < 8) atomicAdd(&pred[lane], ps);
    }
    __syncthreads();
    if (tid == 0) {
        double aux = 0.0;
#pragma unroll
        for (int e = 0; e < NEXP; e++)
            aux += ((double)sc1[e] / n) * ((double)pred[e] / n);
        *aux_out = (float)(aux * NEXP);
    }
#pragma unroll
    for (int e = 0; e < NEXP; e++)
        for (int r = sc2[e] + tid; r < segc[e]; r += 256)
            row_tok[segb[e] + r] = -1;
    __syncthreads();

    for (int base = 0; base < n; base += 256) {
        int t = base + tid;
        int e0 = top_e[t * 2 + 0];
        int e1 = top_e[t * 2 + 1];
        unsigned long long below = (lane == 63) ? ~0ull >> 1 : (1ull << lane) - 1;
        int r0 = 0, r1 = 0;
#pragma unroll
        for (int e = 0; e < NEXP; e++) {
            unsigned long long m0 = __ballot(e0 == e);
            unsigned long long m1 = __ballot(e1 == e);
            if (e0 == e) r0 = __popcll(m0 & below);
            if (e1 == e) r1 = __popcll(m1 & below);
            if (lane == 0) {
                woff[wave][e] = __popcll(m0);
                woff[wave][8 + e] = __popcll(m1);
            }
        }
        __syncthreads();
        int pre0 = 0, tot0_e1 = 0, pre1 = 0;
#pragma unroll
        for (int w = 0; w < 4; w++) {
            if (w < wave) pre0 += woff[w][e0];
            tot0_e1 += woff[w][e1];
            if (w < wave) pre1 += woff[w][8 + e1];
        }
        int row0 = cur[e0] + pre0 + r0;
        int row1 = cur[e1] + tot0_e1 + pre1 + r1;
        row_tok[row0] = t;
        row_tok[row1] = t;
        row_of[t * 2 + 0] = row0;
        row_of[t * 2 + 1] = row1;
        __syncthreads();
        if (tid < 8)
            cur[tid] += woff[0][tid] + woff[1][tid] + woff[2][tid] + woff[3][tid]
                      + woff[0][8 + tid] + woff[1][8 + tid] + woff[2][8 + tid]
                      + woff[3][8 + tid];
        __syncthreads();
    }
}

// ------- per-expert transpose-convert [R][C]f32 -> [C][R]bf16, 64x64 tiles ----
__global__ __launch_bounds__(256) void transpose_cvt_kernel(
    const float* __restrict__ src, bf16_t* __restrict__ dst, int R, int C)
{
    __shared__ float tile[64][65];
    int e = blockIdx.z;
    int r0 = blockIdx.y * 64, c0 = blockIdx.x * 64;
    int tid = threadIdx.x;

    int r = tid >> 4;              // 0..15
    int cq = (tid & 15) * 4;       // 0..60
    const float* s = src + ((size_t)e * R + r0 + r) * C + c0 + cq;
#pragma unroll
    for (int j = 0; j < 4; j++) {
        float4 v = *(const float4*)(s + (size_t)j * 16 * C);
        tile[r + j * 16][cq + 0] = v.x;
        tile[r + j * 16][cq + 1] = v.y;
        tile[r + j * 16][cq + 2] = v.z;
        tile[r + j * 16][cq + 3] = v.w;
    }
    __syncthreads();

    int c = tid >> 2;              // 0..63
    int rq = (tid & 3) * 16;       // 0,16,32,48
    bf16_t* d = dst + ((size_t)e * C + c0 + c) * R + r0 + rq;
    bf16x8 o0, o1;
#pragma unroll
    for (int j = 0; j < 8; j++) o0[j] = (bf16_t)tile[rq + j][c];
#pragma unroll
    for (int j = 0; j < 8; j++) o1[j] = (bf16_t)tile[rq + 8 + j][c];
    *(bf16x8*)(d + 0) = o0;
    *(bf16x8*)(d + 8) = o1;
}

// ---------------- expert lookup ----------------------------------------------
__device__ __forceinline__ int tile_expert(const int* hdr, int row0)
{
    int e = -1;
#pragma unroll
    for (int i = 0; i < NEXP; i++) {
        int sb = hdr[24 + i];
        if (row0 >= sb && row0 < sb + hdr[32 + i]) e = i;
    }
    if (e >= 0 && row0 - hdr[24 + e] >= hdr[e]) e = -1;
    return e;
}

// ---------------- GEMM1: Hbuf = silu(X[rows] @ W1[e]) bf16 MFMA ---------------
// BK=64, m97 structure: 32 MFMA per barrier pair, 16KB+16KB LDS tiles.
// Swizzle: phys_chunk = logical_chunk ^ (row&7); row stride 128B so a 16-lane
// ds_read_b128 phase hits 8 distinct bank-quads x 2 lanes (free 2-way).
// Applied on global source at staging (linear global_load_lds dest) and on
// the ds_read address — same involution both sides.
__global__ __launch_bounds__(256) void gemm1_kernel(
    const bf16_t* __restrict__ xbf, const bf16_t* __restrict__ w1t,
    const int* __restrict__ hdr, const int* __restrict__ row_tok,
    bf16_t* __restrict__ Hbuf)
{
    __shared__ __align__(16) bf16_t As[BM * BK];
    __shared__ __align__(16) bf16_t Bs[BN * BK];

    int row0 = blockIdx.x * BM;
    int e = tile_expert(hdr, row0);
    if (e < 0) return;
    int n0 = blockIdx.y * BN;
    int tid = threadIdx.x;

    // staging: issue i covers slots i*256+tid; row = i*32 + (tid>>3), p = tid&7
    int sr = tid >> 3, sp = tid & 7;
    int sc = sp ^ (sr & 7);            // logical chunk, invariant over i
    const bf16_t* wb = w1t + (size_t)e * HIDDEN * INTER;
    const bf16_t* ag[4];
    const bf16_t* bg[4];
    bf16_t* al[4];
    bf16_t* bl[4];
#pragma unroll
    for (int i = 0; i < 4; i++) {
        int r = i * 32 + sr;
        int t = row_tok[row0 + r]; if (t < 0) t = 0;
        ag[i] = xbf + (size_t)t * HIDDEN + sc * 8;
        bg[i] = wb + (size_t)(n0 + r) * HIDDEN + sc * 8;
        al[i] = As + (i * 256 + tid) * 8;
        bl[i] = Bs + (i * 256 + tid) * 8;
    }

    int wave = tid >> 6, lane = tid & 63;
    int wm = (wave >> 1) * 64, wn = (wave & 1) * 64;
    int lrow = lane & 15, q = lane >> 4;

    int aoff[4][2], boff[4][2];
#pragma unroll
    for (int i = 0; i < 4; i++) {
#pragma unroll
        for (int h = 0; h < 2; h++) {
            int r = wm + i * 16 + lrow;
            aoff[i][h] = r * BK + ((h * 4 + q) ^ (r & 7)) * 8;
            int s = wn + i * 16 + lrow;
            boff[i][h] = s * BK + ((h * 4 + q) ^ (s & 7)) * 8;
        }
    }

    f32x4 acc[4][4] = {};

    for (int k0 = 0; k0 < HIDDEN; k0 += BK) {
#pragma unroll
        for (int i = 0; i < 4; i++) async_cp16(ag[i] + k0, al[i]);
#pragma unroll
        for (int i = 0; i < 4; i++) async_cp16(bg[i] + k0, bl[i]);
        __syncthreads();
#pragma unroll
        for (int h = 0; h < 2; h++) {
            bf16x8 af[4], bfr[4];
#pragma unroll
            for (int i = 0; i < 4; i++) {
                af[i]  = *(const bf16x8*)(As + aoff[i][h]);
                bfr[i] = *(const bf16x8*)(Bs + boff[i][h]);
            }
#pragma unroll
            for (int mi = 0; mi < 4; mi++)
#pragma unroll
                for (int nj = 0; nj < 4; nj++)
                    acc[mi][nj] = __builtin_amdgcn_mfma_f32_16x16x32_bf16(
                        bfr[nj], af[mi], acc[mi][nj], 0, 0, 0);
        }
        __syncthreads();
    }

#pragma unroll
    for (int mi = 0; mi < 4; mi++) {
        size_t rb = (size_t)(row0 + wm + mi * 16 + lrow) * INTER + n0 + wn + q * 4;
#pragma unroll
        for (int nj = 0; nj < 4; nj++) {
            f32x4 v = acc[mi][nj];
            bf16x4 o = {
                (bf16_t)(v.x * __builtin_amdgcn_rcpf(1.f + __expf(-v.x))),
                (bf16_t)(v.y * __builtin_amdgcn_rcpf(1.f + __expf(-v.y))),
                (bf16_t)(v.z * __builtin_amdgcn_rcpf(1.f + __expf(-v.z))),
                (bf16_t)(v.w * __builtin_amdgcn_rcpf(1.f + __expf(-v.w))) };
            *(bf16x4*)(Hbuf + rb + nj * 16) = o;
        }
    }
}

// ---------------- GEMM2: Obuf = Hbuf[rows] @ W2[e] ----------------------------
__global__ __launch_bounds__(256) void gemm2_kernel(
    const bf16_t* __restrict__ Hbuf, const bf16_t* __restrict__ w2t,
    const int* __restrict__ hdr, bf16_t* __restrict__ Obuf)
{
    __shared__ __align__(16) bf16_t As[BM * BK];
    __shared__ __align__(16) bf16_t Bs[BN * BK];

    int row0 = blockIdx.x * BM;
    int e = tile_expert(hdr, row0);
    if (e < 0) return;
    int n0 = blockIdx.y * BN;
    int tid = threadIdx.x;

    int sr = tid >> 3, sp = tid & 7;
    int sc = sp ^ (sr & 7);
    const bf16_t* wb = w2t + (size_t)e * HIDDEN * INTER;
    const bf16_t* ag[4];
    const bf16_t* bg[4];
    bf16_t* al[4];
    bf16_t* bl[4];
#pragma unroll
    for (int i = 0; i < 4; i++) {
        int r = i * 32 + sr;
        ag[i] = Hbuf + (size_t)(row0 + r) * INTER + sc * 8;
        bg[i] = wb + (size_t)(n0 + r) * INTER + sc * 8;
        al[i] = As + (i * 256 + tid) * 8;
        bl[i] = Bs + (i * 256 + tid) * 8;
    }

    int wave = tid >> 6, lane = tid & 63;
    int wm = (wave >> 1) * 64, wn = (wave & 1) * 64;
    int lrow = lane & 15, q = lane >> 4;

    int aoff[4][2], boff[4][2];
#pragma unroll
    for (int i = 0; i < 4; i++) {
#pragma unroll
        for (int h = 0; h < 2; h++) {
            int r = wm + i * 16 + lrow;
            aoff[i][h] = r * BK + ((h * 4 + q) ^ (r & 7)) * 8;
            int s = wn + i * 16 + lrow;
            boff[i][h] = s * BK + ((h * 4 + q) ^ (s & 7)) * 8;
        }
    }

    f32x4 acc[4][4] = {};

    for (int k0 = 0; k0 < INTER; k0 += BK) {
#pragma unroll
        for (int i = 0; i < 4; i++) async_cp16(ag[i] + k0, al[i]);
#pragma unroll
        for (int i = 0; i < 4; i++) async_cp16(bg[i] + k0, bl[i]);
        __syncthreads();
#pragma unroll
        for (int h = 0; h < 2; h++) {
            bf16x8 af[4], bfr[4];
#pragma unroll
            for (int i = 0; i < 4; i++) {
                af[i]  = *(const bf16x8*)(As + aoff[i][h]);
                bfr[i] = *(const bf16x8*)(Bs + boff[i][h]);
            }
#pragma unroll
            for (int mi = 0; mi < 4; mi++)
#pragma unroll
                for (int nj = 0; nj < 4; nj++)
                    acc[mi][nj] = __builtin_amdgcn_mfma_f32_16x16x32_bf16(
                        bfr[nj], af[mi], acc[mi][nj], 0, 0, 0);
        }
        __syncthreads();
    }

#pragma unroll
    for (int mi = 0; mi < 4; mi++) {
        size_t rb = (size_t)(row0 + wm + mi * 16 + lrow) * HIDDEN + n0 + wn + q * 4;
#pragma unroll
        for (int nj = 0; nj < 4; nj++) {
            f32x4 v = acc[mi][nj];
            bf16x4 o = { (bf16_t)v.x, (bf16_t)v.y, (bf16_t)v.z, (bf16_t)v.w };
            *(bf16x4*)(Obuf + rb + nj * 16) = o;
        }
    }
}

// ---------------- Combine: out[t] = w0*Obuf[r0] + w1*Obuf[r1] -----------------
__global__ __launch_bounds__(256) void combine_kernel(
    const bf16_t* __restrict__ Obuf, const int* __restrict__ row_of,
    const float* __restrict__ top_w, float* __restrict__ out)
{
    int t = blockIdx.x;
    int r0 = row_of[t * 2 + 0], r1 = row_of[t * 2 + 1];
    float w0 = top_w[t * 2 + 0], w1 = top_w[t * 2 + 1];
    int c = threadIdx.x * 4;
    bf16x4 a = *(const bf16x4*)(Obuf + (size_t)r0 * HIDDEN + c);
    bf16x4 b = *(const bf16x4*)(Obuf + (size_t)r1 * HIDDEN + c);
    float4 o;
    o.x = w0 * (float)a.x + w1 * (float)b.x;
    o.y = w0 * (float)a.y + w1 * (float)b.y;
    o.z = w0 * (float)a.z + w1 * (float)b.z;
    o.w = w0 * (float)a.w + w1 * (float)b.w;
    *(float4*)(out + (size_t)t * HIDDEN + c) = o;
}

// ---------------- Launch ------------------------------------------------------
extern "C" void kernel_launch(void* const* d_in, const int* in_sizes, int n_in,
                              void* d_out, int out_size, void* d_ws, size_t ws_size,
                              hipStream_t stream)
{
    const float* x  = (const float*)d_in[0];
    const float* wr = (const float*)d_in[1];
    const float* w1 = (const float*)d_in[2];
    const float* w2 = (const float*)d_in[3];
    float* out = (float*)d_out;

    int n = in_sizes[0] / HIDDEN;                                  // 8192
    int nblk = n / 4;                                              // 2048
    int rowcap = ((2 * n + NEXP * (BM - 1)) + BM - 1) / BM * BM;   // 17408

    char* ws = (char*)d_ws;
    int* hdr = (int*)ws;
    size_t off = 512;
    int* row_tok = (int*)(ws + off); off += (size_t)rowcap * 4;
    int* row_of  = (int*)(ws + off); off += (size_t)n * 2 * 4;
    int* top_e   = (int*)(ws + off); off += (size_t)n * 2 * 4;
    float* top_w = (float*)(ws + off); off += (size_t)n * 2 * 4;
    float* psums = (float*)(ws + off); off += (size_t)nblk * NEXP * 4;
    off = (off + 255) & ~(size_t)255;
    size_t xbf_off = off;
    bf16_t* xbf = (bf16_t*)(ws + off);  off += (size_t)n * HIDDEN * 2;
    bf16_t* w1t = (bf16_t*)(ws + off);  off += (size_t)NEXP * HIDDEN * INTER * 2;
    bf16_t* w2t = (bf16_t*)(ws + off);  off += (size_t)NEXP * HIDDEN * INTER * 2;
    bf16_t* Hbuf = (bf16_t*)(ws + off); off += (size_t)rowcap * INTER * 2;
    bf16_t* Obuf = (bf16_t*)(ws + xbf_off);   // aliases xbf+w1t (dead after gemm1)

    router_kernel<<<nblk, 256, 0, stream>>>(x, wr, top_e, top_w, psums, xbf);
    transpose_cvt_kernel<<<dim3(INTER / 64, HIDDEN / 64, NEXP), 256, 0, stream>>>(
        w1, w1t, HIDDEN, INTER);
    transpose_cvt_kernel<<<dim3(HIDDEN / 64, INTER / 64, NEXP), 256, 0, stream>>>(
        w2, w2t, INTER, HIDDEN);
    setup_scatter_kernel<<<1, 256, 0, stream>>>(top_e, psums, nblk, hdr,
                                                row_tok, row_of,
                                                out + (out_size - 1), n);

    dim3 g1(rowcap / BM, INTER / BN);
    gemm1_kernel<<<g1, 256, 0, stream>>>(xbf, w1t, hdr, row_tok, Hbuf);
    dim3 g2(rowcap / BM, HIDDEN / BN);
    gemm2_kernel<<<g2, 256, 0, stream>>>(Hbuf, w2t, hdr, Obuf);
    combine_kernel<<<n, 256, 0, stream>>>(Obuf, row_of, top_w, out);
}